// Round 1
// baseline (235.891 us; speedup 1.0000x reference)
//
#include <hip/hip_runtime.h>
#include <cstddef>

// Problem constants (B,C,H,W)=(4,3,512,512), E=192, p=2 -> grid 256x256, K=12.
// R5: restructure for occupancy. Split patchify into P[b][i][j][12] (12.6 MB in
// d_ws, L2-resident), then fused kernel per HALF row: 12.4 KB LDS (was 49.4),
// dinv via selects (was 80 rsqrtf/thread), idx-linear coalesced halo reads,
// XCD-chunked swizzle. Phase-2 projection kept verbatim from R4.
constexpr int kH  = 512, kW = 512, kC = 3;
constexpr int kHH = 256, kWW = 256;
constexpr int kN  = kHH * kWW;
constexpr int kE  = 192, kK = 12, kB = 4;

typedef float nt_f4 __attribute__((ext_vector_type(4)));

__device__ __forceinline__ float dinvf(int i, int j) {
    // in-degree incl. self-loop: interior 5, edge 4, corner 3
    const int deg = 1 + (i > 0) + (i < kHH - 1) + (j > 0) + (j < kWW - 1);
    float r = 0.44721359549995794f;            // 1/sqrt(5)
    if (deg == 4) r = 0.5f;                    // 1/sqrt(4)
    if (deg == 3) r = 0.5773502691896258f;     // 1/sqrt(3)
    return r;
}

// M[e][k] = sum_j gcn_w[e][j] * conv_w[j][k]   (conv_w flattened [192][12])
__global__ __launch_bounds__(64) void build_M(const float* __restrict__ gcn_w,
                                              const float* __restrict__ conv_w,
                                              float* __restrict__ M) {
    const int e = blockIdx.x;
    const int lane = threadIdx.x;
    float acc[kK];
#pragma unroll
    for (int k = 0; k < kK; ++k) acc[k] = 0.f;
    for (int j = lane; j < kE; j += 64) {
        const float g = gcn_w[e * kE + j];
        const float4 c0 = *(const float4*)(conv_w + j * kK + 0);
        const float4 c1 = *(const float4*)(conv_w + j * kK + 4);
        const float4 c2 = *(const float4*)(conv_w + j * kK + 8);
        acc[0] += g * c0.x; acc[1] += g * c0.y; acc[2]  += g * c0.z; acc[3]  += g * c0.w;
        acc[4] += g * c1.x; acc[5] += g * c1.y; acc[6]  += g * c1.z; acc[7]  += g * c1.w;
        acc[8] += g * c2.x; acc[9] += g * c2.y; acc[10] += g * c2.z; acc[11] += g * c2.w;
    }
#pragma unroll
    for (int k = 0; k < kK; ++k) {
        float v = acc[k];
#pragma unroll
        for (int off = 32; off > 0; off >>= 1) v += __shfl_down(v, off);
        if (lane == 0) M[e * kK + k] = v;
    }
}

// P[b][i][j][k] = x[b][c][2i+u][2j+v], k = c*4+u*2+v. Pure gather, fully
// coalesced (float2 in, float4 out). Plain stores -> P stays L2-resident.
__global__ __launch_bounds__(256) void patchify(const float* __restrict__ x,
                                                float* __restrict__ P) {
    const int i = blockIdx.x & (kHH - 1);
    const int b = blockIdx.x >> 8;
    const int j = threadIdx.x;
    float p[12];
#pragma unroll
    for (int c = 0; c < kC; ++c)
#pragma unroll
        for (int u = 0; u < 2; ++u) {
            const float2 t2 = *(const float2*)(x + ((size_t)(b * kC + c) * kH + (2 * i + u)) * kW + 2 * j);
            p[c * 4 + u * 2 + 0] = t2.x;
            p[c * 4 + u * 2 + 1] = t2.y;
        }
    float* dst = P + ((size_t)(b * kHH + i) * kWW + j) * kK;
    *(float4*)(dst + 0) = make_float4(p[0], p[1], p[2],  p[3]);
    *(float4*)(dst + 4) = make_float4(p[4], p[5], p[6],  p[7]);
    *(float4*)(dst + 8) = make_float4(p[8], p[9], p[10], p[11]);
}

// Fused aggregate+project: one block = one HALF node row (128 nodes).
// Phase 0: stage center P row + 1-node halo each side into LDS (6.2 KB).
// Phase 1: agg[j][k] from LDS (center/left/right) + global (up/down, idx-linear
//          coalesced, used exactly once per block so no staging needed).
// Phase 2: out = M * agg + bias, M register-resident (4 rows/thread), nt stores.
constexpr int THREADS = 192;
constexpr int JB      = 128;    // nodes per block

__global__ __launch_bounds__(THREADS, 4) void fused_gcn(
        const float* __restrict__ P, const float* __restrict__ M,
        const float* __restrict__ bias, float* __restrict__ out) {
    __shared__ float s_P[(JB + 2) * kK];   // 6240 B
    __shared__ float s_agg[JB][kK];        // 6144 B

    const int t = threadIdx.x;

    // XCD-chunked bijective swizzle (grid 2048 = 8 XCDs x 256): each XCD gets
    // 128 consecutive rows of one batch -> vertical-halo P reads are L2-local.
    const int bid  = (int)blockIdx.x;
    const int wg   = (bid & 7) * 256 + (bid >> 3);
    const int half = wg & 1;
    const int i    = (wg >> 1) & (kHH - 1);
    const int b    = wg >> 9;
    const int j0   = half * JB;

    // Per-thread fixed output channels e..e+3; M rows -> registers.
    const int e4  = t % 48;
    const int sub = t / 48;   // 0..3
    const int e   = e4 * 4;
    float4 mrow[12];
#pragma unroll
    for (int r = 0; r < 12; ++r) mrow[r] = ((const float4*)(M + (size_t)e * kK))[r];
    const float4 bv = *(const float4*)(bias + e);

    // ---- Phase 0: stage P[i][j0-1 .. j0+128] (130 nodes = 390 float4)
    const float* Prow = P + ((long long)(b * kHH + i) * kWW + (j0 - 1)) * kK;
#pragma unroll
    for (int q = 0; q < 3; ++q) {
        const int f4 = t + q * THREADS;
        if (f4 < 3 * (JB + 2)) {
            const int node = f4 / 3;            // 0..129
            const int jg   = j0 - 1 + node;
            float4 v = make_float4(0.f, 0.f, 0.f, 0.f);
            if (jg >= 0 && jg < kWW)
                v = *(const float4*)(Prow + (long long)f4 * 4);
            *(float4*)(&s_P[f4 * 4]) = v;
        }
    }
    __syncthreads();

    // ---- Phase 1: 1536 entries = 8 per thread, entry idx = j*12+k (linear)
    const float* Pu = P + ((long long)(b * kHH + (i - 1)) * kWW + j0) * kK;
    const float* Pd = P + ((long long)(b * kHH + (i + 1)) * kWW + j0) * kK;
#pragma unroll
    for (int q = 0; q < 8; ++q) {
        const int idx = t + q * THREADS;
        const int j   = idx / kK;
        const int k   = idx - j * kK;
        const int jg  = j0 + j;
        const float pc = s_P[(j + 1) * kK + k];
        const float pl = s_P[ j      * kK + k];   // zeroed halo at jg==0
        const float pr = s_P[(j + 2) * kK + k];   // zeroed halo at jg==255
        float pu = 0.f, pd = 0.f;
        if (i > 0)       pu = Pu[idx];            // coalesced dword loads
        if (i < kHH - 1) pd = Pd[idx];
        const float dc = dinvf(i, jg);
        float s = dc * pc;
        s += dinvf(i - 1, jg) * pu;
        s += dinvf(i + 1, jg) * pd;
        s += dinvf(i, jg - 1) * pl;
        s += dinvf(i, jg + 1) * pr;
        s_agg[j][k] = dc * s;
    }
    __syncthreads();

    // ---- Phase 2: project 12 -> 192, contiguous 98 KB store per block
    float* outb = out + ((size_t)b * kN + (size_t)i * kWW + j0) * kE + e;
#pragma unroll 4
    for (int it = 0; it < JB / 4; ++it) {
        const int nl = it * 4 + sub;
        const float4 a0 = *((const float4*)&s_agg[nl][0]);
        const float4 a1 = *((const float4*)&s_agg[nl][4]);
        const float4 a2 = *((const float4*)&s_agg[nl][8]);
        nt_f4 acc;
#pragma unroll
        for (int r = 0; r < 4; ++r) {
            const float4 m0 = mrow[r * 3 + 0];
            const float4 m1 = mrow[r * 3 + 1];
            const float4 m2 = mrow[r * 3 + 2];
            float s = ((const float*)&bv)[r];
            s += m0.x * a0.x + m0.y * a0.y + m0.z * a0.z + m0.w * a0.w;
            s += m1.x * a1.x + m1.y * a1.y + m1.z * a1.z + m1.w * a1.w;
            s += m2.x * a2.x + m2.y * a2.y + m2.z * a2.z + m2.w * a2.w;
            acc[r] = s;
        }
        __builtin_nontemporal_store(acc, (nt_f4*)(outb + (size_t)nl * kE));
    }
}

extern "C" void kernel_launch(void* const* d_in, const int* in_sizes, int n_in,
                              void* d_out, int out_size, void* d_ws, size_t ws_size,
                              hipStream_t stream) {
    const float* x      = (const float*)d_in[0];  // [4,3,512,512]
    const float* conv_w = (const float*)d_in[1];  // [192,3,2,2] -> [192][12]
    const float* gcn_w  = (const float*)d_in[2];  // [192,192]
    const float* gcn_b  = (const float*)d_in[3];  // [192]
    float* out = (float*)d_out;                   // [4, 65536, 192] fp32
    float* M   = (float*)d_ws;                    // 2304 floats (9216 B)
    float* P   = (float*)d_ws + 2304;             // 12.6 MB patch vectors

    build_M<<<kE, 64, 0, stream>>>(gcn_w, conv_w, M);
    patchify<<<kB * kHH, 256, 0, stream>>>(x, P);
    fused_gcn<<<kB * kHH * 2, THREADS, 0, stream>>>(P, M, gcn_b, out);
}

// Round 2
// 232.447 us; speedup vs baseline: 1.0148x; 1.0148x over previous
//
#include <hip/hip_runtime.h>
#include <cstddef>

// Problem constants (B,C,H,W)=(4,3,512,512), E=192, p=2 -> grid 256x256, K=12.
// R6: collapse back to 2 launches. Half-row blocks (R5 occupancy) but stage the
// raw x window (6 rows x 3 ch x 268 cols = 19.1 KB, halo zero-filled) instead
// of the P round-trip -> patchify kernel deleted, phase 1 is pure LDS with no
// conditionals and no global loads. Phase 2 projection verbatim from R4/R5.
constexpr int kH  = 512, kW = 512, kC = 3;
constexpr int kHH = 256, kWW = 256;
constexpr int kN  = kHH * kWW;
constexpr int kE  = 192, kK = 12, kB = 4;

typedef float nt_f4 __attribute__((ext_vector_type(4)));

__device__ __forceinline__ float dinvf(int i, int j) {
    // in-degree incl. self-loop: interior 5, edge 4, corner 3 (branch-free)
    const int deg = 1 + (i > 0) + (i < kHH - 1) + (j > 0) + (j < kWW - 1);
    float r = 0.44721359549995794f;            // 1/sqrt(5)
    if (deg == 4) r = 0.5f;                    // 1/sqrt(4)
    if (deg == 3) r = 0.5773502691896258f;     // 1/sqrt(3)
    return r;
}

// M[e][k] = sum_j gcn_w[e][j] * conv_w[j][k]   (conv_w flattened [192][12])
__global__ __launch_bounds__(64) void build_M(const float* __restrict__ gcn_w,
                                              const float* __restrict__ conv_w,
                                              float* __restrict__ M) {
    const int e = blockIdx.x;
    const int lane = threadIdx.x;
    float acc[kK];
#pragma unroll
    for (int k = 0; k < kK; ++k) acc[k] = 0.f;
    for (int j = lane; j < kE; j += 64) {
        const float g = gcn_w[e * kE + j];
        const float4 c0 = *(const float4*)(conv_w + j * kK + 0);
        const float4 c1 = *(const float4*)(conv_w + j * kK + 4);
        const float4 c2 = *(const float4*)(conv_w + j * kK + 8);
        acc[0] += g * c0.x; acc[1] += g * c0.y; acc[2]  += g * c0.z; acc[3]  += g * c0.w;
        acc[4] += g * c1.x; acc[5] += g * c1.y; acc[6]  += g * c1.z; acc[7]  += g * c1.w;
        acc[8] += g * c2.x; acc[9] += g * c2.y; acc[10] += g * c2.z; acc[11] += g * c2.w;
    }
#pragma unroll
    for (int k = 0; k < kK; ++k) {
        float v = acc[k];
#pragma unroll
        for (int off = 32; off > 0; off >>= 1) v += __shfl_down(v, off);
        if (lane == 0) M[e * kK + k] = v;
    }
}

// Fused patchify+aggregate+project: one block = one HALF node row (128 nodes).
// Phase 0: stage x rows 2i-2..2i+3, 3 ch, cols 2*j0-4..2*j0+263 into LDS
//          (aligned float4, halo zero-filled -> phase 1 needs no clipping).
// Phase 1: s_agg[j][k] = dinv-normalized 5-point patch aggregation, pure LDS.
// Phase 2: out = M * agg + bias, M register-resident (4 rows/thread), nt stores.
constexpr int THREADS = 192;
constexpr int JB      = 128;    // nodes per block
constexpr int XPITCH  = 272;    // 268 staged floats per (c,row), padded

__global__ __launch_bounds__(THREADS, 4) void fused_gcn(
        const float* __restrict__ x, const float* __restrict__ M,
        const float* __restrict__ bias, float* __restrict__ out) {
    __shared__ float s_x[kC * 6 * XPITCH];   // 19584 B
    __shared__ float s_agg[JB][kK];          // 6144 B

    const int t = threadIdx.x;

    // XCD-chunked bijective swizzle (grid 2048 = 8 XCDs x 256): each XCD owns
    // 128 consecutive node rows of one batch -> x window reads stay L2-local.
    const int bid  = (int)blockIdx.x;
    const int wg   = (bid & 7) * 256 + (bid >> 3);
    const int half = wg & 1;
    const int i    = (wg >> 1) & (kHH - 1);
    const int b    = wg >> 9;
    const int j0   = half * JB;

    // Per-thread fixed output channels e..e+3; M rows -> registers.
    const int e4  = t % 48;
    const int sub = t / 48;   // 0..3
    const int e   = e4 * 4;
    float4 mrow[12];
#pragma unroll
    for (int r = 0; r < 12; ++r) mrow[r] = ((const float4*)(M + (size_t)e * kK))[r];
    const float4 bv = *(const float4*)(bias + e);

    // ---- Phase 0: 18 (c,row) segments x 67 aligned float4 = 1206 slots
    const int g0 = 2 * j0 - 4;    // leftmost staged float col (may be <0)
    const int r0 = 2 * i - 2;     // topmost staged pixel row  (may be <0)
#pragma unroll
    for (int q = 0; q < 7; ++q) {
        const int s = t + q * THREADS;
        if (s < 18 * 67) {
            const int cr = s / 67, f = s - cr * 67;
            const int c = cr / 6, row = cr - c * 6;
            const int rg = r0 + row;
            const int gc = g0 + f * 4;
            float4 v = make_float4(0.f, 0.f, 0.f, 0.f);
            if (rg >= 0 && rg < kH && gc >= 0 && gc + 3 < kW)
                v = *(const float4*)(x + ((size_t)(b * kC + c) * kH + rg) * kW + gc);
            *(float4*)&s_x[(c * 6 + row) * XPITCH + f * 4] = v;
        }
    }
    __syncthreads();

    // ---- Phase 1: 1536 entries = 8/thread, idx = j*12+k; zero halos -> no ifs
#pragma unroll
    for (int q = 0; q < 8; ++q) {
        const int idx = t + q * THREADS;
        const int j   = idx / kK;
        const int k   = idx - j * kK;
        const int c = k >> 2, u = (k >> 1) & 1, v = k & 1;
        const int jg = j0 + j;
        const int cc = 2 * j + v + 4;          // center col in stage coords
        const float* sc = &s_x[(c * 6) * XPITCH];
        const float pc = sc[(u + 2) * XPITCH + cc];
        const float pu = sc[(u    ) * XPITCH + cc];      // zero rows at i==0
        const float pd = sc[(u + 4) * XPITCH + cc];      // zero rows at i==255
        const float pl = sc[(u + 2) * XPITCH + cc - 2];  // zero cols at jg==0
        const float pr = sc[(u + 2) * XPITCH + cc + 2];  // zero cols at jg==255
        const float dc = dinvf(i, jg);
        float s2 = dc * pc
                 + dinvf(i - 1, jg) * pu
                 + dinvf(i + 1, jg) * pd
                 + dinvf(i, jg - 1) * pl
                 + dinvf(i, jg + 1) * pr;
        s_agg[j][k] = dc * s2;
    }
    __syncthreads();

    // ---- Phase 2: project 12 -> 192, contiguous 98 KB store per block
    float* outb = out + ((size_t)b * kN + (size_t)i * kWW + j0) * kE + e;
#pragma unroll 4
    for (int it = 0; it < JB / 4; ++it) {
        const int nl = it * 4 + sub;
        const float4 a0 = *((const float4*)&s_agg[nl][0]);
        const float4 a1 = *((const float4*)&s_agg[nl][4]);
        const float4 a2 = *((const float4*)&s_agg[nl][8]);
        nt_f4 acc;
#pragma unroll
        for (int r = 0; r < 4; ++r) {
            const float4 m0 = mrow[r * 3 + 0];
            const float4 m1 = mrow[r * 3 + 1];
            const float4 m2 = mrow[r * 3 + 2];
            float s = ((const float*)&bv)[r];
            s += m0.x * a0.x + m0.y * a0.y + m0.z * a0.z + m0.w * a0.w;
            s += m1.x * a1.x + m1.y * a1.y + m1.z * a1.z + m1.w * a1.w;
            s += m2.x * a2.x + m2.y * a2.y + m2.z * a2.z + m2.w * a2.w;
            acc[r] = s;
        }
        __builtin_nontemporal_store(acc, (nt_f4*)(outb + (size_t)nl * kE));
    }
}

extern "C" void kernel_launch(void* const* d_in, const int* in_sizes, int n_in,
                              void* d_out, int out_size, void* d_ws, size_t ws_size,
                              hipStream_t stream) {
    const float* x      = (const float*)d_in[0];  // [4,3,512,512]
    const float* conv_w = (const float*)d_in[1];  // [192,3,2,2] -> [192][12]
    const float* gcn_w  = (const float*)d_in[2];  // [192,192]
    const float* gcn_b  = (const float*)d_in[3];  // [192]
    float* out = (float*)d_out;                   // [4, 65536, 192] fp32
    float* M   = (float*)d_ws;                    // 2304 floats (9216 B)

    build_M<<<kE, 64, 0, stream>>>(gcn_w, conv_w, M);
    fused_gcn<<<kB * kHH * 2, THREADS, 0, stream>>>(x, M, gcn_b, out);
}